// Round 11
// baseline (372.484 us; speedup 1.0000x reference)
//
#include <hip/hip_runtime.h>

#define BATCH 16
#define NINST 8              // instance labels 1..8; 0 = background
#define NPB   (720 * 1280)   // elements per batch = 921600
#define NV4   (NPB / 4)      // float4 items per batch = 230400
#define BPB   60             // blocks per batch
#define GRID  (BATCH * BPB)  // 960 blocks <= 4/CU * 256 CU = 1024 (co-residency guaranteed)
#define EPT   15             // float4 per thread: 256*15 = 3840 per block; 60*3840 = NV4
#define NELEM (EPT * 4)      // 60 elements per thread
#define MARGIN_VAR  0.5f
#define MARGIN_DIST 3.0f

// ws floats: [0..127] cnt[b][l], [128..255] sum[b][l], [256..383] psum[b][l], [384] barrier ctr

__global__ __launch_bounds__(256, 4) void k_fused(const float4* __restrict__ x,
                                                  const int4* __restrict__ g,
                                                  float* __restrict__ ws) {
    const int tid = threadIdx.x;
    const int bx  = blockIdx.x;
    const int b   = bx / BPB;
    const size_t base = (size_t)b * NV4 + (size_t)(bx % BPB) * (256 * EPT) + tid;

    uint pk[8];    // 60 labels x 4 bits
    uint xb[30];   // 60 x values as packed bf16
#pragma unroll
    for (int i = 0; i < 8; ++i) pk[i] = 0u;
#pragma unroll
    for (int i = 0; i < 30; ++i) xb[i] = 0u;

    float s[NINST];
#pragma unroll
    for (int l = 0; l < NINST; ++l) s[l] = 0.f;
    uint c0 = 0u, c1 = 0u;   // 4x 8-bit count fields each (max 60 per field)

    // ---- single sweep: load x+g once; accumulate count/sum; stash bf16(x)+label ----
#pragma unroll
    for (int k = 0; k < EPT; ++k) {
        float4 xv = x[base + (size_t)k * 256];
        int4   gv = g[base + (size_t)k * 256];
#pragma unroll
        for (int e = 0; e < 4; ++e) {
            int   li = (e == 0) ? gv.x : (e == 1) ? gv.y : (e == 2) ? gv.z : gv.w;
            float xx = (e == 0) ? xv.x : (e == 1) ? xv.y : (e == 2) ? xv.z : xv.w;
            uint l = ((unsigned)li <= NINST) ? (uint)li : 0u;   // ignore/OOR -> background
            const int j = 4 * k + e;                            // compile-time constant
            pk[j >> 3] |= l << (4 * (j & 7));
            uint ub = (__float_as_uint(xx) + 0x8000u) >> 16;    // round-to-nearest bf16
            xb[j >> 1] |= ub << (16 * (j & 1));
#pragma unroll
            for (int q = 1; q <= NINST; ++q) s[q - 1] += (l == (uint)q) ? xx : 0.f;
            uint inc = 1u << (((l - 1) & 3u) * 8);
            c0 += (l >= 1u && l <= 4u) ? inc : 0u;
            c1 += (l >= 5u) ? inc : 0u;
        }
    }

    // unpack counts, wave64 reduce 16 values
    float c[NINST];
#pragma unroll
    for (int l = 0; l < 4; ++l) {
        c[l]     = (float)((c0 >> (8 * l)) & 0xFFu);
        c[l + 4] = (float)((c1 >> (8 * l)) & 0xFFu);
    }
#pragma unroll
    for (int l = 0; l < NINST; ++l) {
#pragma unroll
        for (int off = 32; off; off >>= 1) {
            s[l] += __shfl_down(s[l], off);
            c[l] += __shfl_down(c[l], off);
        }
    }

    __shared__ float red[4][2 * NINST];
    const int lane = tid & 63, wid = tid >> 6;
    if (lane == 0) {
#pragma unroll
        for (int l = 0; l < NINST; ++l) {
            red[wid][l]         = c[l];
            red[wid][NINST + l] = s[l];
        }
    }
    __syncthreads();
    if (tid < 2 * NINST) {
        float v = red[0][tid] + red[1][tid] + red[2][tid] + red[3][tid];
        int l     = tid & (NINST - 1);
        int isSum = tid >> 3;
        atomicAdd(&ws[isSum * 128 + b * NINST + l], v);
    }

    // ---- manual grid barrier (all 960 blocks co-resident by construction) ----
    unsigned* bar = (unsigned*)(ws + 384);
    __threadfence();          // drain this lane's global ops (incl. the atomics above)
    __syncthreads();
    if (tid == 0) {
        __hip_atomic_fetch_add(bar, 1u, __ATOMIC_ACQ_REL, __HIP_MEMORY_SCOPE_AGENT);
        while (__hip_atomic_load(bar, __ATOMIC_ACQUIRE, __HIP_MEMORY_SCOPE_AGENT) < (unsigned)GRID)
            __builtin_amdgcn_s_sleep(2);
    }
    __syncthreads();

    // ---- per-batch means (agent-scope loads: coherent across XCDs) ----
    __shared__ float smu[NINST + 1];
    if (tid == 8) smu[0] = 0.f;
    if (tid < NINST) {
        float cnt = __hip_atomic_load(&ws[b * NINST + tid],
                                      __ATOMIC_RELAXED, __HIP_MEMORY_SCOPE_AGENT);
        float sum = __hip_atomic_load(&ws[128 + b * NINST + tid],
                                      __ATOMIC_RELAXED, __HIP_MEMORY_SCOPE_AGENT);
        smu[1 + tid] = sum / fmaxf(cnt, 1.f);
    }
    __syncthreads();

    // ---- phase 2: pull hinge from register-held bf16 x + packed labels ----
    float p[NINST];
#pragma unroll
    for (int l = 0; l < NINST; ++l) p[l] = 0.f;

#pragma unroll
    for (int k = 0; k < EPT; ++k) {
#pragma unroll
        for (int e = 0; e < 4; ++e) {
            const int j = 4 * k + e;
            uint l = (pk[j >> 3] >> (4 * (j & 7))) & 0xFu;
            float xx = __uint_as_float(((xb[j >> 1] >> (16 * (j & 1))) & 0xFFFFu) << 16);
            float t  = fmaxf(fabsf(xx - smu[l]) - MARGIN_VAR, 0.f);
            float pe = t * t;
#pragma unroll
            for (int q = 1; q <= NINST; ++q) p[q - 1] += (l == (uint)q) ? pe : 0.f;
        }
    }

#pragma unroll
    for (int l = 0; l < NINST; ++l) {
#pragma unroll
        for (int off = 32; off; off >>= 1)
            p[l] += __shfl_down(p[l], off);
    }

    __shared__ float red2[4][NINST];
    if (lane == 0) {
#pragma unroll
        for (int l = 0; l < NINST; ++l) red2[wid][l] = p[l];
    }
    __syncthreads();
    if (tid < NINST) {
        float v = red2[0][tid] + red2[1][tid] + red2[2][tid] + red2[3][tid];
        atomicAdd(&ws[256 + b * NINST + tid], v);
    }
}

__global__ __launch_bounds__(128) void k_final(const float* __restrict__ ws,
                                               float* __restrict__ out) {
    const int tid = threadIdx.x;        // 0..127 = b*8 + l
    const int b = tid >> 3;

    float cnt = ws[tid];
    float sum = ws[128 + tid];
    float ps  = ws[256 + tid];
    float valid  = (cnt > 0.f) ? 1.f : 0.f;
    float mean   = sum / fmaxf(cnt, 1.f);
    float pull_i = ps / fmaxf(cnt, 1.f);

    __shared__ float smean[128];
    __shared__ float svalid[128];
    smean[tid]  = mean;
    svalid[tid] = valid;
    __syncthreads();

    float ploss = 0.f, npush = 0.f;
#pragma unroll
    for (int j = 0; j < NINST; ++j) {
        if (j == (tid & 7)) continue;
        float pv = valid * svalid[b * NINST + j];
        float d  = fabsf(mean - smean[b * NINST + j]);
        float t  = fmaxf(2.f * MARGIN_DIST - d, 0.f);
        ploss += pv * t * t;
        npush += pv;
    }

    float vals[4] = {pull_i * valid, valid, ploss, npush};
#pragma unroll
    for (int k = 0; k < 4; ++k) {
#pragma unroll
        for (int off = 32; off; off >>= 1)
            vals[k] += __shfl_down(vals[k], off);
    }

    __shared__ float r2[2][4];
    const int lane = tid & 63, wid = tid >> 6;
    if (lane == 0) {
#pragma unroll
        for (int k = 0; k < 4; ++k) r2[wid][k] = vals[k];
    }
    __syncthreads();
    if (tid == 0) {
        float pulls = r2[0][0] + r2[1][0];
        float npl   = r2[0][1] + r2[1][1];
        float pls   = r2[0][2] + r2[1][2];
        float nps   = r2[0][3] + r2[1][3];
        float pull_loss = (npl > 0.f) ? pulls / fmaxf(npl, 1.f) : 0.f;
        float push_loss = (nps > 0.f) ? pls / fmaxf(nps, 1.f) : 0.f;
        out[0] = push_loss + pull_loss;
    }
}

extern "C" void kernel_launch(void* const* d_in, const int* in_sizes, int n_in,
                              void* d_out, int out_size, void* d_ws, size_t ws_size,
                              hipStream_t stream) {
    const float4* x4 = (const float4*)d_in[0];
    const int4*   g4 = (const int4*)d_in[1];
    float* out = (float*)d_out;
    float* ws  = (float*)d_ws;

    hipMemsetAsync(d_ws, 0, 512 * sizeof(float), stream);   // cnt/sum/psum + barrier ctr

    k_fused<<<dim3(GRID), dim3(256), 0, stream>>>(x4, g4, ws);
    k_final<<<1, 128, 0, stream>>>(ws, out);
}

// Round 12
// 322.392 us; speedup vs baseline: 1.1554x; 1.1554x over previous
//
#include <hip/hip_runtime.h>

#define BATCH 16
#define NINST 8              // instance labels 1..8; 0 = background
#define NPB   (720 * 1280)   // elements per batch = 921600
#define NV4   (NPB / 4)      // float4 items per batch = 230400
#define BPB   60             // blocks per batch
#define GRID  (BATCH * BPB)  // 960 blocks <= 4/CU * 256 CU (co-resident; LDS allows 5/CU)
#define EPT   15             // float4 per thread: 256*15*60 = NV4
#define MARGIN_VAR  0.5f
#define MARGIN_DIST 3.0f

// ws floats: [0..127] cnt[b][l], [128..255] sum[b][l], [256..383] psum[b][l], [384] barrier ctr

__global__ __launch_bounds__(256, 4) void k_fused(const float4* __restrict__ x,
                                                  const int4* __restrict__ g,
                                                  float* __restrict__ ws) {
    __shared__ uint  sx[256 * EPT * 2];      // 7680 uints = 30 KB: bf16-pair stash of x
    __shared__ float red[4][2 * NINST];
    __shared__ float red2[4][NINST];
    __shared__ float smu[NINST + 1];

    const int tid = threadIdx.x;
    const int bx  = blockIdx.x;
    const int b   = bx / BPB;
    const size_t base = (size_t)b * NV4 + (size_t)(bx % BPB) * (256 * EPT) + tid;

    uint pk[8];    // 60 labels x 4 bits (statically indexed after unroll)
#pragma unroll
    for (int i = 0; i < 8; ++i) pk[i] = 0u;

    float s[NINST];
#pragma unroll
    for (int l = 0; l < NINST; ++l) s[l] = 0.f;
    uint c0 = 0u, c1 = 0u;   // 4x 8-bit count fields each (max 60 per field)

    // ---- single global sweep: count/sum in f32; stash bf16(x) to LDS, labels to regs ----
#pragma unroll
    for (int k = 0; k < EPT; ++k) {
        float4 xv = x[base + (size_t)k * 256];
        int4   gv = g[base + (size_t)k * 256];
        uint u0 = (__float_as_uint(xv.x) + 0x8000u) >> 16;
        uint u1 = (__float_as_uint(xv.y) + 0x8000u) >> 16;
        uint u2 = (__float_as_uint(xv.z) + 0x8000u) >> 16;
        uint u3 = (__float_as_uint(xv.w) + 0x8000u) >> 16;
        sx[(k * 256 + tid) * 2]     = u0 | (u1 << 16);
        sx[(k * 256 + tid) * 2 + 1] = u2 | (u3 << 16);
#pragma unroll
        for (int e = 0; e < 4; ++e) {
            int   li = (e == 0) ? gv.x : (e == 1) ? gv.y : (e == 2) ? gv.z : gv.w;
            float xx = (e == 0) ? xv.x : (e == 1) ? xv.y : (e == 2) ? xv.z : xv.w;
            uint l = ((unsigned)li <= NINST) ? (uint)li : 0u;   // ignore/OOR -> background
            const int j = 4 * k + e;
            pk[j >> 3] |= l << (4 * (j & 7));
#pragma unroll
            for (int q = 1; q <= NINST; ++q) s[q - 1] += (l == (uint)q) ? xx : 0.f;
            uint inc = 1u << (((l - 1) & 3u) * 8);
            c0 += (l >= 1u && l <= 4u) ? inc : 0u;
            c1 += (l >= 5u) ? inc : 0u;
        }
    }

    // unpack counts, wave64 reduce 16 values
    float c[NINST];
#pragma unroll
    for (int l = 0; l < 4; ++l) {
        c[l]     = (float)((c0 >> (8 * l)) & 0xFFu);
        c[l + 4] = (float)((c1 >> (8 * l)) & 0xFFu);
    }
#pragma unroll
    for (int l = 0; l < NINST; ++l) {
#pragma unroll
        for (int off = 32; off; off >>= 1) {
            s[l] += __shfl_down(s[l], off);
            c[l] += __shfl_down(c[l], off);
        }
    }

    const int lane = tid & 63, wid = tid >> 6;
    if (lane == 0) {
#pragma unroll
        for (int l = 0; l < NINST; ++l) {
            red[wid][l]         = c[l];
            red[wid][NINST + l] = s[l];
        }
    }
    __syncthreads();
    if (tid < 2 * NINST) {
        float v = red[0][tid] + red[1][tid] + red[2][tid] + red[3][tid];
        int l     = tid & (NINST - 1);
        int isSum = tid >> 3;
        atomicAdd(&ws[isSum * 128 + b * NINST + l], v);
    }

    // ---- manual grid barrier (all 960 blocks co-resident by construction) ----
    unsigned* bar = (unsigned*)(ws + 384);
    __threadfence();          // drain this lane's global ops (incl. the atomics above)
    __syncthreads();
    if (tid == 0) {
        __hip_atomic_fetch_add(bar, 1u, __ATOMIC_ACQ_REL, __HIP_MEMORY_SCOPE_AGENT);
        while (__hip_atomic_load(bar, __ATOMIC_ACQUIRE, __HIP_MEMORY_SCOPE_AGENT) < (unsigned)GRID)
            __builtin_amdgcn_s_sleep(2);
    }
    __syncthreads();

    // ---- per-batch means (agent-scope loads: coherent across XCDs) ----
    if (tid == 8) smu[0] = 0.f;
    if (tid < NINST) {
        float cnt = __hip_atomic_load(&ws[b * NINST + tid],
                                      __ATOMIC_RELAXED, __HIP_MEMORY_SCOPE_AGENT);
        float sum = __hip_atomic_load(&ws[128 + b * NINST + tid],
                                      __ATOMIC_RELAXED, __HIP_MEMORY_SCOPE_AGENT);
        smu[1 + tid] = sum / fmaxf(cnt, 1.f);
    }
    __syncthreads();

    // ---- phase 2: pull hinge from LDS-stashed bf16 x + packed labels ----
    float p[NINST];
#pragma unroll
    for (int l = 0; l < NINST; ++l) p[l] = 0.f;

#pragma unroll
    for (int k = 0; k < EPT; ++k) {
        uint w0 = sx[(k * 256 + tid) * 2];
        uint w1 = sx[(k * 256 + tid) * 2 + 1];
#pragma unroll
        for (int e = 0; e < 4; ++e) {
            const int j = 4 * k + e;
            uint l = (pk[j >> 3] >> (4 * (j & 7))) & 0xFu;
            uint uw = (e < 2) ? w0 : w1;
            float xx = __uint_as_float(((uw >> (16 * (e & 1))) & 0xFFFFu) << 16);
            float t  = fmaxf(fabsf(xx - smu[l]) - MARGIN_VAR, 0.f);
            float pe = t * t;
#pragma unroll
            for (int q = 1; q <= NINST; ++q) p[q - 1] += (l == (uint)q) ? pe : 0.f;
        }
    }

#pragma unroll
    for (int l = 0; l < NINST; ++l) {
#pragma unroll
        for (int off = 32; off; off >>= 1)
            p[l] += __shfl_down(p[l], off);
    }

    if (lane == 0) {
#pragma unroll
        for (int l = 0; l < NINST; ++l) red2[wid][l] = p[l];
    }
    __syncthreads();
    if (tid < NINST) {
        float v = red2[0][tid] + red2[1][tid] + red2[2][tid] + red2[3][tid];
        atomicAdd(&ws[256 + b * NINST + tid], v);
    }
}

__global__ __launch_bounds__(128) void k_final(const float* __restrict__ ws,
                                               float* __restrict__ out) {
    const int tid = threadIdx.x;        // 0..127 = b*8 + l
    const int b = tid >> 3;

    float cnt = ws[tid];
    float sum = ws[128 + tid];
    float ps  = ws[256 + tid];
    float valid  = (cnt > 0.f) ? 1.f : 0.f;
    float mean   = sum / fmaxf(cnt, 1.f);
    float pull_i = ps / fmaxf(cnt, 1.f);

    __shared__ float smean[128];
    __shared__ float svalid[128];
    smean[tid]  = mean;
    svalid[tid] = valid;
    __syncthreads();

    float ploss = 0.f, npush = 0.f;
#pragma unroll
    for (int j = 0; j < NINST; ++j) {
        if (j == (tid & 7)) continue;
        float pv = valid * svalid[b * NINST + j];
        float d  = fabsf(mean - smean[b * NINST + j]);
        float t  = fmaxf(2.f * MARGIN_DIST - d, 0.f);
        ploss += pv * t * t;
        npush += pv;
    }

    float vals[4] = {pull_i * valid, valid, ploss, npush};
#pragma unroll
    for (int k = 0; k < 4; ++k) {
#pragma unroll
        for (int off = 32; off; off >>= 1)
            vals[k] += __shfl_down(vals[k], off);
    }

    __shared__ float r2[2][4];
    const int lane = tid & 63, wid = tid >> 6;
    if (lane == 0) {
#pragma unroll
        for (int k = 0; k < 4; ++k) r2[wid][k] = vals[k];
    }
    __syncthreads();
    if (tid == 0) {
        float pulls = r2[0][0] + r2[1][0];
        float npl   = r2[0][1] + r2[1][1];
        float pls   = r2[0][2] + r2[1][2];
        float nps   = r2[0][3] + r2[1][3];
        float pull_loss = (npl > 0.f) ? pulls / fmaxf(npl, 1.f) : 0.f;
        float push_loss = (nps > 0.f) ? pls / fmaxf(nps, 1.f) : 0.f;
        out[0] = push_loss + pull_loss;
    }
}

extern "C" void kernel_launch(void* const* d_in, const int* in_sizes, int n_in,
                              void* d_out, int out_size, void* d_ws, size_t ws_size,
                              hipStream_t stream) {
    const float4* x4 = (const float4*)d_in[0];
    const int4*   g4 = (const int4*)d_in[1];
    float* out = (float*)d_out;
    float* ws  = (float*)d_ws;

    hipMemsetAsync(d_ws, 0, 512 * sizeof(float), stream);   // cnt/sum/psum + barrier ctr

    k_fused<<<dim3(GRID), dim3(256), 0, stream>>>(x4, g4, ws);
    k_final<<<1, 128, 0, stream>>>(ws, out);
}

// Round 15
// 195.671 us; speedup vs baseline: 1.9036x; 1.6476x over previous
//
#include <hip/hip_runtime.h>

#define BATCH 16
#define NINST 8              // instance labels 1..8; 0 = background
#define NPB   (720 * 1280)   // elements per batch = 921600
#define NV4   (NPB / 4)      // float4 items per batch = 230400
#define BLKX  225            // 225 blocks * 1024 float4 = NV4 exactly
#define MARGIN_VAR  0.5f
#define MARGIN_DIST 3.0f

// ws layout (floats):
// [0..127]   cnt[b][l]            (k_stats atomics)
// [128..255] sum[b][l]            (k_stats atomics)
// [400..415] pull partial per b   (k_pull2 atomics)
// [440]      push_loss            (k_mid)
// [448..735] (mu,w) float2 per (b, l=0..8): idx 448 + (b*9+l)*2   (k_mid)

__device__ __forceinline__ void acc_stats(float4 xv, int4 gv,
                                          float (&s)[NINST], int (&cw)[NINST]) {
#pragma unroll
    for (int e = 0; e < 4; ++e) {
        int   li = (e == 0) ? gv.x : (e == 1) ? gv.y : (e == 2) ? gv.z : gv.w;
        float xx = (e == 0) ? xv.x : (e == 1) ? xv.y : (e == 2) ? xv.z : xv.w;
        int l = ((unsigned)li <= NINST) ? li : 0;
#pragma unroll
        for (int q = 1; q <= NINST; ++q) {
            bool eq = (l == q);
            s[q - 1] += eq ? xx : 0.f;
            cw[q - 1] += (int)__popcll(__ballot(eq));   // wave-uniform -> SALU
        }
    }
}

__global__ __launch_bounds__(256) void k_stats(const float4* __restrict__ x,
                                               const int4* __restrict__ g,
                                               float* __restrict__ ws) {
    const int tid = threadIdx.x;
    const int b = blockIdx.y;
    const size_t base = (size_t)b * NV4 + (size_t)blockIdx.x * 1024 + tid;

    float4 xv0 = x[base];
    float4 xv1 = x[base + 256];
    float4 xv2 = x[base + 512];
    float4 xv3 = x[base + 768];
    int4   gv0 = g[base];
    int4   gv1 = g[base + 256];
    int4   gv2 = g[base + 512];
    int4   gv3 = g[base + 768];

    float s[NINST];
    int   cw[NINST];
#pragma unroll
    for (int l = 0; l < NINST; ++l) { s[l] = 0.f; cw[l] = 0; }

    acc_stats(xv0, gv0, s, cw);
    acc_stats(xv1, gv1, s, cw);
    acc_stats(xv2, gv2, s, cw);
    acc_stats(xv3, gv3, s, cw);

    // sums: wave64 shuffle reduce; counts: already wave-total (uniform)
#pragma unroll
    for (int l = 0; l < NINST; ++l) {
#pragma unroll
        for (int off = 32; off; off >>= 1)
            s[l] += __shfl_down(s[l], off);
    }

    __shared__ float red[4][2 * NINST];
    const int lane = tid & 63, wid = tid >> 6;
    if (lane == 0) {
#pragma unroll
        for (int l = 0; l < NINST; ++l) {
            red[wid][l]         = (float)cw[l];
            red[wid][NINST + l] = s[l];
        }
    }
    __syncthreads();
    if (tid < 2 * NINST) {
        float v = red[0][tid] + red[1][tid] + red[2][tid] + red[3][tid];
        int l     = tid & (NINST - 1);
        int isSum = tid >> 3;   // 0 -> cnt, 1 -> sum
        atomicAdd(&ws[isSum * 128 + b * NINST + l], v);
    }
}

// single block, 128 threads: push loss + (mu, w) table
__global__ __launch_bounds__(128) void k_mid(float* __restrict__ ws) {
    const int tid = threadIdx.x;        // b*8 + l
    const int b = tid >> 3;

    float cnt = ws[tid];
    float sum = ws[128 + tid];
    float valid = (cnt > 0.f) ? 1.f : 0.f;
    float mean  = sum / fmaxf(cnt, 1.f);

    __shared__ float smean[128];
    __shared__ float svalid[128];
    smean[tid]  = mean;
    svalid[tid] = valid;
    __syncthreads();

    float ploss = 0.f, npush = 0.f;
#pragma unroll
    for (int j = 0; j < NINST; ++j) {
        if (j == (tid & 7)) continue;
        float pv = valid * svalid[b * NINST + j];
        float d  = fabsf(mean - smean[b * NINST + j]);
        float t  = fmaxf(2.f * MARGIN_DIST - d, 0.f);
        ploss += pv * t * t;
        npush += pv;
    }

    float vals[3] = {valid, ploss, npush};
#pragma unroll
    for (int k = 0; k < 3; ++k) {
#pragma unroll
        for (int off = 32; off; off >>= 1)
            vals[k] += __shfl_down(vals[k], off);
    }

    __shared__ float r2[2][3];
    __shared__ float snp;
    const int lane = tid & 63, wid = tid >> 6;
    if (lane == 0) {
#pragma unroll
        for (int k = 0; k < 3; ++k) r2[wid][k] = vals[k];
    }
    __syncthreads();
    if (tid == 0) {
        float npl = r2[0][0] + r2[1][0];
        float pls = r2[0][1] + r2[1][1];
        float nps = r2[0][2] + r2[1][2];
        ws[440] = (nps > 0.f) ? pls / fmaxf(nps, 1.f) : 0.f;   // push_loss
        snp = npl;                                              // n_pull
    }
    __syncthreads();

    float n_pull = snp;
    float w = (n_pull > 0.f) ? valid / (fmaxf(cnt, 1.f) * n_pull) : 0.f;
    float2* mw = (float2*)(ws + 448);
    mw[b * 9 + (tid & 7) + 1] = make_float2(mean, w);
    if (tid < BATCH) mw[tid * 9] = make_float2(0.f, 0.f);   // background entry
}

__device__ __forceinline__ void acc_pull(float4 xv, int4 gv,
                                         const float2* __restrict__ smw,
                                         float& acc) {
#pragma unroll
    for (int e = 0; e < 4; ++e) {
        int   li = (e == 0) ? gv.x : (e == 1) ? gv.y : (e == 2) ? gv.z : gv.w;
        float xx = (e == 0) ? xv.x : (e == 1) ? xv.y : (e == 2) ? xv.z : xv.w;
        int l = ((unsigned)li <= NINST) ? li : 0;
        float2 mw = smw[l];
        float t = fmaxf(fabsf(xx - mw.x) - MARGIN_VAR, 0.f);
        acc = fmaf(t * t, mw.y, acc);
    }
}

__global__ __launch_bounds__(256) void k_pull2(const float4* __restrict__ x,
                                               const int4* __restrict__ g,
                                               float* __restrict__ ws) {
    const int tid = threadIdx.x;
    const int b = blockIdx.y;
    const size_t base = (size_t)b * NV4 + (size_t)blockIdx.x * 1024 + tid;

    float4 xv0 = x[base];
    float4 xv1 = x[base + 256];
    float4 xv2 = x[base + 512];
    float4 xv3 = x[base + 768];
    int4   gv0 = g[base];
    int4   gv1 = g[base + 256];
    int4   gv2 = g[base + 512];
    int4   gv3 = g[base + 768];

    __shared__ float2 smw[16];   // 9 used
    if (tid < 9) smw[tid] = ((const float2*)(ws + 448))[b * 9 + tid];
    __syncthreads();

    float acc = 0.f;
    acc_pull(xv0, gv0, smw, acc);
    acc_pull(xv1, gv1, smw, acc);
    acc_pull(xv2, gv2, smw, acc);
    acc_pull(xv3, gv3, smw, acc);

#pragma unroll
    for (int off = 32; off; off >>= 1)
        acc += __shfl_down(acc, off);

    __shared__ float red[4];
    const int lane = tid & 63, wid = tid >> 6;
    if (lane == 0) red[wid] = acc;
    __syncthreads();
    if (tid == 0) {
        float v = red[0] + red[1] + red[2] + red[3];
        atomicAdd(&ws[400 + b], v);
    }
}

__global__ __launch_bounds__(64) void k_final2(const float* __restrict__ ws,
                                               float* __restrict__ out) {
    const int tid = threadIdx.x;
    float v = (tid < BATCH) ? ws[400 + tid] : 0.f;
#pragma unroll
    for (int off = 8; off; off >>= 1)
        v += __shfl_down(v, off);
    if (tid == 0) out[0] = ws[440] + v;
}

extern "C" void kernel_launch(void* const* d_in, const int* in_sizes, int n_in,
                              void* d_out, int out_size, void* d_ws, size_t ws_size,
                              hipStream_t stream) {
    const float4* x4 = (const float4*)d_in[0];
    const int4*   g4 = (const int4*)d_in[1];
    float* out = (float*)d_out;
    float* ws  = (float*)d_ws;

    hipMemsetAsync(d_ws, 0, 3072, stream);   // 768 floats cover all ws slots used

    dim3 grid(BLKX, BATCH);
    k_stats<<<grid, 256, 0, stream>>>(x4, g4, ws);
    k_mid<<<1, 128, 0, stream>>>(ws);
    k_pull2<<<grid, 256, 0, stream>>>(x4, g4, ws);
    k_final2<<<1, 64, 0, stream>>>(ws, out);
}